// Round 2
// baseline (49.552 us; speedup 1.0000x reference)
//
#include <hip/hip_runtime.h>

#define DIMS 64
#define KF 16
#define ROWS 4

__global__ __launch_bounds__(256, 4) void fm_fwd_kernel(
    const int* __restrict__ user,
    const int* __restrict__ item,
    const float* __restrict__ user_emb,
    const float* __restrict__ item_emb,
    const float* __restrict__ w1,
    const float* __restrict__ b1,
    const float* __restrict__ v,
    float* __restrict__ out,
    int B)
{
    const int lane = threadIdx.x & 63;
    const int wv   = threadIdx.x >> 6;
    const int base = (blockIdx.x * 4 + wv) * ROWS;
    if (base >= B) return;

    // Wave-uniform index loads (base is uniform -> scalar loads)
    int uix[ROWS], iix[ROWS];
    #pragma unroll
    for (int r = 0; r < ROWS; ++r) {
        uix[r] = user[base + r];
        iix[r] = item[base + r];
    }

    // 8 independent coalesced 256B gathers, all in flight together
    float xa[ROWS], xb[ROWS];
    #pragma unroll
    for (int r = 0; r < ROWS; ++r) {
        xa[r] = user_emb[(size_t)uix[r] * DIMS + lane];
        xb[r] = item_emb[(size_t)iix[r] * DIMS + lane];
    }

    // v rows for this lane's two feature elements (8KB table, L1-hot);
    // loaded ONCE per wave, reused for 4 rows.
    const float4* va4 = (const float4*)(v + (size_t)lane * KF);
    const float4* vb4 = (const float4*)(v + (size_t)(DIMS + lane) * KF);
    float va[KF], vb[KF];
    #pragma unroll
    for (int i = 0; i < 4; ++i) {
        float4 a = va4[i], b = vb4[i];
        va[4*i+0]=a.x; va[4*i+1]=a.y; va[4*i+2]=a.z; va[4*i+3]=a.w;
        vb[4*i+0]=b.x; vb[4*i+1]=b.y; vb[4*i+2]=b.z; vb[4*i+3]=b.w;
    }
    const float wa = w1[lane], wb = w1[DIMS + lane];
    const float bias = b1[0];

    // Per row: s[k] partials -> 4-mask vector-halving (15 shfl) ->
    // finish S_k over 16/32 masks (2 shfl) -> fold everything into one
    // per-lane scalar q[r]:  out[r] = bias + sum_lanes q[r]
    float q[ROWS];
    #pragma unroll
    for (int r = 0; r < ROWS; ++r) {
        const float a = xa[r], b = xb[r];
        const float a2 = a * a, b2 = b * b;
        float s[KF];
        float t = 0.f;
        #pragma unroll
        for (int k = 0; k < KF; ++k) {
            s[k] = a * va[k] + b * vb[k];
            t += a2 * (va[k] * va[k]) + b2 * (vb[k] * vb[k]);
        }
        const float lin = a * wa + b * wb;

        int n = KF;
        #pragma unroll
        for (int step = 0; step < 4; ++step) {
            n >>= 1;
            const int m = 1 << step;
            const bool hi = (lane & m) != 0;
            #pragma unroll
            for (int i = 0; i < n; ++i) {
                float keep = hi ? s[n + i] : s[i];
                float send = hi ? s[i] : s[n + i];
                s[i] = keep + __shfl_xor(send, m, 64);
            }
        }
        float sv = s[0];
        sv += __shfl_xor(sv, 16, 64);
        sv += __shfl_xor(sv, 32, 64);
        // sum_lanes sv^2 = 4 * sum_k S_k^2 ; pairwise = 0.5*(sum_k S_k^2 - sum_lanes t)
        q[r] = lin + 0.125f * (sv * sv) - 0.5f * t;
    }

    // Combined cross-row reduction: 2-step vector halving over rows (3 shfl)
    // then 4-mask butterfly (4 shfl). After this, lane c (c = lane&3) holds
    // the full sum for row ((c&1)<<1)|((c>>1)&1).
    float r0, r1;
    {
        const bool hi = (lane & 1) != 0;
        float k0 = hi ? q[2] : q[0], s0 = hi ? q[0] : q[2];
        float k1 = hi ? q[3] : q[1], s1 = hi ? q[1] : q[3];
        r0 = k0 + __shfl_xor(s0, 1, 64);
        r1 = k1 + __shfl_xor(s1, 1, 64);
    }
    float rr;
    {
        const bool hi = (lane & 2) != 0;
        float k = hi ? r1 : r0, s = hi ? r0 : r1;
        rr = k + __shfl_xor(s, 2, 64);
    }
    rr += __shfl_xor(rr, 4, 64);
    rr += __shfl_xor(rr, 8, 64);
    rr += __shfl_xor(rr, 16, 64);
    rr += __shfl_xor(rr, 32, 64);

    if (lane < 4) {
        const int row = ((lane & 1) << 1) | ((lane >> 1) & 1);
        if (base + row < B)
            out[base + row] = rr + bias;
    }
}

extern "C" void kernel_launch(void* const* d_in, const int* in_sizes, int n_in,
                              void* d_out, int out_size, void* d_ws, size_t ws_size,
                              hipStream_t stream) {
    const int*   user     = (const int*)  d_in[0];
    const int*   item     = (const int*)  d_in[1];
    const float* user_emb = (const float*)d_in[2];
    const float* item_emb = (const float*)d_in[3];
    const float* w1       = (const float*)d_in[4];
    const float* b1       = (const float*)d_in[5];
    const float* v        = (const float*)d_in[6];
    float* out = (float*)d_out;

    const int B = in_sizes[0];
    const int rows_per_block = 4 * ROWS;  // 4 waves x ROWS rows
    const int blocks = (B + rows_per_block - 1) / rows_per_block;
    fm_fwd_kernel<<<blocks, 256, 0, stream>>>(user, item, user_emb, item_emb,
                                              w1, b1, v, out, B);
}

// Round 3
// 15.064 us; speedup vs baseline: 3.2893x; 3.2893x over previous
//
#include <hip/hip_runtime.h>

#define DIMS 64
#define KF 16

// DPP-based lane permute: result[lane] = x[perm(lane)] — pure VALU, no LDS pipe.
template<int CTRL>
__device__ __forceinline__ float dppmv(float x) {
    return __builtin_bit_cast(float,
        __builtin_amdgcn_update_dpp(0, __builtin_bit_cast(int, x), CTRL, 0xF, 0xF, true));
}
// Single-instruction LDS-crossbar swizzle (no per-lane address VGPR).
template<int PAT>
__device__ __forceinline__ float swzf(float x) {
    return __builtin_bit_cast(float,
        __builtin_amdgcn_ds_swizzle(__builtin_bit_cast(int, x), PAT));
}

#define DPP_XOR1  0xB1   // quad_perm(1,0,3,2)
#define DPP_XOR2  0x4E   // quad_perm(2,3,0,1)
#define DPP_XOR8  0x128  // row_ror:8  (i+8 mod 16 == i^8)
#define SWZ_XOR4  0x101F // BitMode xor_mask=4
#define SWZ_XOR16 0x401F // BitMode xor_mask=16

__global__ __launch_bounds__(256, 4) void fm_fwd_kernel(
    const int* __restrict__ user,
    const int* __restrict__ item,
    const float* __restrict__ user_emb,
    const float* __restrict__ item_emb,
    const float* __restrict__ w1,
    const float* __restrict__ b1,
    const float* __restrict__ v,
    float* __restrict__ out,
    int B)
{
    const int lane = threadIdx.x & 63;
    const int wv   = threadIdx.x >> 6;
    const int row  = blockIdx.x * 4 + wv;
    if (row >= B) return;

    const int u  = user[row];
    const int it = item[row];

    // coalesced 256B gathers: lane l -> x[l] (user), x[64+l] (item)
    const float xa = user_emb[(size_t)u  * DIMS + lane];
    const float xb = item_emb[(size_t)it * DIMS + lane];

    // v rows for this lane's two feature elements (8KB, L1-hot)
    const float4* va4 = (const float4*)(v + (size_t)lane * KF);
    const float4* vb4 = (const float4*)(v + (size_t)(DIMS + lane) * KF);
    float va[KF], vb[KF];
    #pragma unroll
    for (int i = 0; i < 4; ++i) {
        float4 a = va4[i], b = vb4[i];
        va[4*i+0]=a.x; va[4*i+1]=a.y; va[4*i+2]=a.z; va[4*i+3]=a.w;
        vb[4*i+0]=b.x; vb[4*i+1]=b.y; vb[4*i+2]=b.z; vb[4*i+3]=b.w;
    }
    const float wa = w1[lane], wb = w1[DIMS + lane];
    const float bias = b1[0];

    // Per-lane sums of squares of v rows (constant per lane): T collapses to
    // a^2*A + b^2*B.
    float A = 0.f, Bq = 0.f;
    #pragma unroll
    for (int k = 0; k < KF; ++k) {
        A  += va[k] * va[k];
        Bq += vb[k] * vb[k];
    }

    float s[KF];
    #pragma unroll
    for (int k = 0; k < KF; ++k)
        s[k] = xa * va[k] + xb * vb[k];

    // c = lin - 0.5*t folded per-lane; out = bias + sum_lanes(c) + 0.5*sum_k S_k^2
    float c = xa * wa + xb * wb - 0.5f * (xa * xa * A + xb * xb * Bq);

    // ---- vector-halving reduce of s over masks 1,2,4,8 (DPP/swizzle mix) ----
    #define HALVE(MV, M, N)                                  \
    {                                                        \
        const bool hi = (lane & (M)) != 0;                   \
        _Pragma("unroll")                                    \
        for (int i = 0; i < (N); ++i) {                      \
            float keep = hi ? s[(N)+i] : s[i];               \
            float send = hi ? s[i] : s[(N)+i];               \
            s[i] = keep + MV(send);                          \
        }                                                    \
    }
    HALVE(dppmv<DPP_XOR1>, 1, 8)
    HALVE(dppmv<DPP_XOR2>, 2, 4)
    HALVE(swzf<SWZ_XOR4>,  4, 2)
    HALVE(dppmv<DPP_XOR8>, 8, 1)
    #undef HALVE

    // finish S_k across the four 16-lane blocks -> every lane: global S_{k(lane)}
    float sv = s[0];
    sv += swzf<SWZ_XOR16>(sv);
    sv += __shfl_xor(sv, 32, 64);

    // butterfly c over all 64 lanes (3 DPP + 2 swizzle + 1 shfl)
    c += dppmv<DPP_XOR1>(c);
    c += dppmv<DPP_XOR2>(c);
    c += swzf<SWZ_XOR4>(c);
    c += dppmv<DPP_XOR8>(c);
    c += swzf<SWZ_XOR16>(c);
    c += __shfl_xor(c, 32, 64);

    // sum the 16 distinct S_k^2 within the 16-lane block
    float val = sv * sv;
    val += dppmv<DPP_XOR1>(val);
    val += dppmv<DPP_XOR2>(val);
    val += swzf<SWZ_XOR4>(val);
    val += dppmv<DPP_XOR8>(val);

    if (lane == 0)
        out[row] = bias + c + 0.5f * val;
}

extern "C" void kernel_launch(void* const* d_in, const int* in_sizes, int n_in,
                              void* d_out, int out_size, void* d_ws, size_t ws_size,
                              hipStream_t stream) {
    const int*   user     = (const int*)  d_in[0];
    const int*   item     = (const int*)  d_in[1];
    const float* user_emb = (const float*)d_in[2];
    const float* item_emb = (const float*)d_in[3];
    const float* w1       = (const float*)d_in[4];
    const float* b1       = (const float*)d_in[5];
    const float* v        = (const float*)d_in[6];
    float* out = (float*)d_out;

    const int B = in_sizes[0];
    const int blocks = (B + 3) / 4;   // 4 waves (1 row each) per 256-thread block
    fm_fwd_kernel<<<blocks, 256, 0, stream>>>(user, item, user_emb, item_emb,
                                              w1, b1, v, out, B);
}

// Round 4
// 14.391 us; speedup vs baseline: 3.4431x; 1.0468x over previous
//
#include <hip/hip_runtime.h>

#define DIMS 64
#define KF 16

// DPP-based lane permute: result[lane] = x[perm(lane)] — pure VALU, no LDS pipe.
template<int CTRL>
__device__ __forceinline__ float dppmv(float x) {
    return __builtin_bit_cast(float,
        __builtin_amdgcn_update_dpp(0, __builtin_bit_cast(int, x), CTRL, 0xF, 0xF, true));
}
// Single-instruction LDS-crossbar swizzle (no per-lane address VGPR).
template<int PAT>
__device__ __forceinline__ float swzf(float x) {
    return __builtin_bit_cast(float,
        __builtin_amdgcn_ds_swizzle(__builtin_bit_cast(int, x), PAT));
}

#define DPP_XOR1  0xB1   // quad_perm(1,0,3,2)
#define DPP_XOR2  0x4E   // quad_perm(2,3,0,1)
#define DPP_XOR8  0x128  // row_ror:8  (i^8 within row of 16)
#define SWZ_XOR4  0x101F // BitMode xor_mask=4
#define SWZ_XOR16 0x401F // BitMode xor_mask=16

__global__ __launch_bounds__(256, 8) void fm_fwd_kernel(
    const int* __restrict__ user,
    const int* __restrict__ item,
    const float* __restrict__ user_emb,
    const float* __restrict__ item_emb,
    const float* __restrict__ w1,
    const float* __restrict__ b1,
    const float* __restrict__ v,
    float* __restrict__ out,
    int B)
{
    const int lane = threadIdx.x & 63;
    // Force wave-uniform row into an SGPR so index/bias loads become s_load
    // on the scalar pipe (issued early, off the vector-mem chain).
    const int row = __builtin_amdgcn_readfirstlane(
        blockIdx.x * 4 + (int)(threadIdx.x >> 6));
    if (row >= B) return;

    const int u  = user[row];   // SGPR address -> s_load
    const int it = item[row];
    const float bias = b1[0];

    // Coalesced 256B gathers, issued ASAP (longest-latency ops: item_emb
    // is 256MB, mostly HBM-miss).
    const float xa = user_emb[(size_t)u  * DIMS + lane];
    const float xb = item_emb[(size_t)it * DIMS + lane];

    const float wa = w1[lane], wb = w1[DIMS + lane];

    // v rows for this lane's two feature elements (8KB table, L1-hot).
    // Loaded in halves-of-8 so va[16]+vb[16] are never fully live: keeps
    // VGPR <= 64 for 8 waves/SIMD.
    const float4* va4 = (const float4*)(v + (size_t)lane * KF);
    const float4* vb4 = (const float4*)(v + (size_t)(DIMS + lane) * KF);

    float s[KF];
    float A = 0.f, Bq = 0.f;   // sum_k va_k^2 , sum_k vb_k^2 (per-lane consts)

    #pragma unroll
    for (int h = 0; h < 2; ++h) {
        float4 a0 = va4[2*h+0], a1 = va4[2*h+1];
        float4 b0 = vb4[2*h+0], b1v = vb4[2*h+1];
        float va[8] = {a0.x,a0.y,a0.z,a0.w,a1.x,a1.y,a1.z,a1.w};
        float vb[8] = {b0.x,b0.y,b0.z,b0.w,b1v.x,b1v.y,b1v.z,b1v.w};
        #pragma unroll
        for (int k = 0; k < 8; ++k) {
            A  += va[k] * va[k];
            Bq += vb[k] * vb[k];
            s[8*h + k] = xa * va[k] + xb * vb[k];
        }
    }

    // Per-lane fold: lin - 0.5*t  (t = xa^2*A + xb^2*Bq)
    float c = xa * wa + xb * wb - 0.5f * (xa * xa * A + xb * xb * Bq);

    // ---- vector-halving reduce of s over masks 1,2,4,8 ----
    #define HALVE(MV, M, N)                                  \
    {                                                        \
        const bool hi = (lane & (M)) != 0;                   \
        _Pragma("unroll")                                    \
        for (int i = 0; i < (N); ++i) {                      \
            float keep = hi ? s[(N)+i] : s[i];               \
            float send = hi ? s[i] : s[(N)+i];               \
            s[i] = keep + MV(send);                          \
        }                                                    \
    }
    HALVE(dppmv<DPP_XOR1>, 1, 8)
    HALVE(dppmv<DPP_XOR2>, 2, 4)
    HALVE(swzf<SWZ_XOR4>,  4, 2)
    HALVE(dppmv<DPP_XOR8>, 8, 1)
    #undef HALVE

    // finish S_k across the four 16-lane blocks
    float sv = s[0];
    sv += swzf<SWZ_XOR16>(sv);
    sv += __shfl_xor(sv, 32, 64);

    // sum_lanes(sv^2) = 4 * sum_k S_k^2  ->  fold into c before ONE butterfly:
    // out = bias + sum_lanes(c + 0.125*sv^2)
    c += 0.125f * (sv * sv);

    c += dppmv<DPP_XOR1>(c);
    c += dppmv<DPP_XOR2>(c);
    c += swzf<SWZ_XOR4>(c);
    c += dppmv<DPP_XOR8>(c);
    c += swzf<SWZ_XOR16>(c);
    c += __shfl_xor(c, 32, 64);

    if (lane == 0)
        out[row] = bias + c;
}

extern "C" void kernel_launch(void* const* d_in, const int* in_sizes, int n_in,
                              void* d_out, int out_size, void* d_ws, size_t ws_size,
                              hipStream_t stream) {
    const int*   user     = (const int*)  d_in[0];
    const int*   item     = (const int*)  d_in[1];
    const float* user_emb = (const float*)d_in[2];
    const float* item_emb = (const float*)d_in[3];
    const float* w1       = (const float*)d_in[4];
    const float* b1       = (const float*)d_in[5];
    const float* v        = (const float*)d_in[6];
    float* out = (float*)d_out;

    const int B = in_sizes[0];
    const int blocks = (B + 3) / 4;   // 4 waves (1 row each) per 256-thread block
    fm_fwd_kernel<<<blocks, 256, 0, stream>>>(user, item, user_emb, item_emb,
                                              w1, b1, v, out, B);
}

// Round 5
// 10.404 us; speedup vs baseline: 4.7627x; 1.3833x over previous
//
#include <hip/hip_runtime.h>

#define DIMS 64
#define KF 16
#define F 128   // 2*DIMS

// DPP lane permute: pure VALU, no LDS pipe, no waitcnt.
template<int CTRL>
__device__ __forceinline__ float dppmv(float x) {
    return __builtin_bit_cast(float,
        __builtin_amdgcn_update_dpp(0, __builtin_bit_cast(int, x), CTRL, 0xF, 0xF, true));
}
// Single-instruction LDS-crossbar swizzle.
template<int PAT>
__device__ __forceinline__ float swzf(float x) {
    return __builtin_bit_cast(float,
        __builtin_amdgcn_ds_swizzle(__builtin_bit_cast(int, x), PAT));
}

#define DPP_XOR1  0xB1   // quad_perm(1,0,3,2)
#define DPP_XOR2  0x4E   // quad_perm(2,3,0,1)
#define DPP_XOR8  0x128  // row_ror:8 (== xor 8 within 16)
#define SWZ_XOR4  0x101F // BitMode xor_mask=4
#define SWZ_XOR16 0x401F // BitMode xor_mask=16

// y = x[l] + x[l^16] in all lanes, pure VALU if permlane16_swap exists.
__device__ __forceinline__ float sum_xor16(float x) {
#if __has_builtin(__builtin_amdgcn_permlane16_swap)
    auto r = __builtin_amdgcn_permlane16_swap(__builtin_bit_cast(int, x),
                                              __builtin_bit_cast(int, x), false, false);
    return __builtin_bit_cast(float, (int)r[0]) + __builtin_bit_cast(float, (int)r[1]);
#else
    return x + swzf<SWZ_XOR16>(x);
#endif
}
// y = x[l] + x[l^32] in all lanes.
__device__ __forceinline__ float sum_xor32(float x) {
#if __has_builtin(__builtin_amdgcn_permlane32_swap)
    auto r = __builtin_amdgcn_permlane32_swap(__builtin_bit_cast(int, x),
                                              __builtin_bit_cast(int, x), false, false);
    return __builtin_bit_cast(float, (int)r[0]) + __builtin_bit_cast(float, (int)r[1]);
#else
    return x + __shfl_xor(x, 32, 64);
#endif
}

__global__ __launch_bounds__(256, 8) void fm_fwd_kernel(
    const int* __restrict__ user,
    const int* __restrict__ item,
    const float* __restrict__ user_emb,
    const float* __restrict__ item_emb,
    const float* __restrict__ w1,
    const float* __restrict__ b1,
    const float* __restrict__ v,
    float* __restrict__ out,
    int B)
{
    __shared__ float vsT[KF * F];   // transposed: vsT[k*F + f] = v[f][k]; 8 KB

    const int tid  = threadIdx.x;
    const int lane = tid & 63;
    const int wv   = tid >> 6;
    // 2 rows per wave; base wave-uniform -> SGPR -> s_load for indices
    const int base = __builtin_amdgcn_readfirstlane((int)blockIdx.x * 8 + wv * 2);

    const int i0 = min(base,     B - 1);
    const int i1 = min(base + 1, B - 1);
    const int u0 = user[i0], t0 = item[i0];
    const int u1 = user[i1], t1 = item[i1];

    // Issue the 4 coalesced 256B row gathers ASAP (longest-latency ops).
    const float xa0 = user_emb[(size_t)u0 * DIMS + lane];
    const float xb0 = item_emb[(size_t)t0 * DIMS + lane];
    const float xa1 = user_emb[(size_t)u1 * DIMS + lane];
    const float xb1 = item_emb[(size_t)t1 * DIMS + lane];
    const float wa = w1[lane], wb = w1[DIMS + lane];
    const float bias = b1[0];

    // Stage v transposed into LDS: one coalesced 8KB global read per block.
    // Write pattern: thread t covers global elements t*8..t*8+7 ->
    // f = t/2, k = 8*(t&1)+j; banks are (f)%32 per instr -> 2-way = free.
    {
        const float4* vg = (const float4*)v;
        float4 p0 = vg[tid * 2 + 0];
        float4 p1 = vg[tid * 2 + 1];
        const int f  = tid >> 1;
        const int k0 = (tid & 1) * 8;
        vsT[(k0+0)*F + f] = p0.x;  vsT[(k0+1)*F + f] = p0.y;
        vsT[(k0+2)*F + f] = p0.z;  vsT[(k0+3)*F + f] = p0.w;
        vsT[(k0+4)*F + f] = p1.x;  vsT[(k0+5)*F + f] = p1.y;
        vsT[(k0+6)*F + f] = p1.z;  vsT[(k0+7)*F + f] = p1.w;
    }
    // LDS-only barrier: don't drain vmcnt (keep row gathers in flight).
    asm volatile("s_waitcnt lgkmcnt(0)" ::: "memory");
    __builtin_amdgcn_s_barrier();

    // k-streamed dot products from LDS. Reads vsT[k*F+lane] / +64 are
    // conflict-free (stride-1 in lane) and pair into ds_read2st64_b32.
    float s0[KF], s1[KF];
    float A = 0.f, Bq = 0.f;
    #pragma unroll
    for (int k = 0; k < KF; ++k) {
        const float va = vsT[k * F + lane];
        const float vb = vsT[k * F + DIMS + lane];
        A  += va * va;
        Bq += vb * vb;
        s0[k] = xa0 * va + xb0 * vb;
        s1[k] = xa1 * va + xb1 * vb;
    }
    float c0 = xa0*wa + xb0*wb - 0.5f*(xa0*xa0*A + xb0*xb0*Bq);
    float c1 = xa1*wa + xb1*wb - 0.5f*(xa1*xa1*A + xb1*xb1*Bq);

    // Vector-halving reduce of s over masks 1,2,8 (DPP) then 4 (1 swizzle),
    // both rows interleaved for ILP. Mask order only permutes the lane->k
    // bijection, which is irrelevant since we sum S_k^2 over all k.
    #define HALVE2(MV, M, N) { \
        const bool hi = (lane & (M)) != 0; \
        _Pragma("unroll") \
        for (int i = 0; i < (N); ++i) { \
            float k0_ = hi ? s0[(N)+i] : s0[i]; float d0_ = hi ? s0[i] : s0[(N)+i]; \
            float k1_ = hi ? s1[(N)+i] : s1[i]; float d1_ = hi ? s1[i] : s1[(N)+i]; \
            s0[i] = k0_ + MV(d0_); \
            s1[i] = k1_ + MV(d1_); \
        } }
    HALVE2(dppmv<DPP_XOR1>, 1, 8)
    HALVE2(dppmv<DPP_XOR2>, 2, 4)
    HALVE2(dppmv<DPP_XOR8>, 8, 2)
    HALVE2(swzf<SWZ_XOR4>,  4, 1)
    #undef HALVE2

    // Finish S_k across the four 16-lane blocks (pure VALU).
    float sv0 = sum_xor32(sum_xor16(s0[0]));
    float sv1 = sum_xor32(sum_xor16(s1[0]));

    // sum_lanes(sv^2) = 4 * sum_k S_k^2 -> fold, then ONE butterfly per row.
    c0 += 0.125f * sv0 * sv0;
    c1 += 0.125f * sv1 * sv1;

    c0 += dppmv<DPP_XOR1>(c0);  c1 += dppmv<DPP_XOR1>(c1);
    c0 += dppmv<DPP_XOR2>(c0);  c1 += dppmv<DPP_XOR2>(c1);
    c0 += swzf<SWZ_XOR4>(c0);   c1 += swzf<SWZ_XOR4>(c1);
    c0 += dppmv<DPP_XOR8>(c0);  c1 += dppmv<DPP_XOR8>(c1);
    c0 = sum_xor16(c0);         c1 = sum_xor16(c1);
    c0 = sum_xor32(c0);         c1 = sum_xor32(c1);

    if (lane == 0) {
        if (base + 1 < B) {
            *(float2*)&out[base] = make_float2(bias + c0, bias + c1);
        } else if (base < B) {
            out[base] = bias + c0;
        }
    }
}

extern "C" void kernel_launch(void* const* d_in, const int* in_sizes, int n_in,
                              void* d_out, int out_size, void* d_ws, size_t ws_size,
                              hipStream_t stream) {
    const int*   user     = (const int*)  d_in[0];
    const int*   item     = (const int*)  d_in[1];
    const float* user_emb = (const float*)d_in[2];
    const float* item_emb = (const float*)d_in[3];
    const float* w1       = (const float*)d_in[4];
    const float* b1       = (const float*)d_in[5];
    const float* v        = (const float*)d_in[6];
    float* out = (float*)d_out;

    const int B = in_sizes[0];
    const int blocks = (B + 7) / 8;   // 4 waves x 2 rows per 256-thread block
    fm_fwd_kernel<<<blocks, 256, 0, stream>>>(user, item, user_emb, item_emb,
                                              w1, b1, v, out, B);
}

// Round 6
// 9.735 us; speedup vs baseline: 5.0902x; 1.0688x over previous
//
#include <hip/hip_runtime.h>

#define DIMS 64
#define KF 16
#define F 128   // 2*DIMS
#define ROWS 4

// DPP lane permute: pure VALU, no LDS pipe, no waitcnt.
template<int CTRL>
__device__ __forceinline__ float dppmv(float x) {
    return __builtin_bit_cast(float,
        __builtin_amdgcn_update_dpp(0, __builtin_bit_cast(int, x), CTRL, 0xF, 0xF, true));
}
// Single-instruction LDS-crossbar swizzle.
template<int PAT>
__device__ __forceinline__ float swzf(float x) {
    return __builtin_bit_cast(float,
        __builtin_amdgcn_ds_swizzle(__builtin_bit_cast(int, x), PAT));
}

#define DPP_XOR1  0xB1   // quad_perm(1,0,3,2)
#define DPP_XOR2  0x4E   // quad_perm(2,3,0,1)
#define DPP_XOR8  0x128  // row_ror:8 (== xor 8 within 16)
#define SWZ_XOR4  0x101F // BitMode xor_mask=4
#define SWZ_XOR16 0x401F // BitMode xor_mask=16

// y[l] = x[l] + x[l^16], pure VALU on gfx950.
__device__ __forceinline__ float sum_xor16(float x) {
#if __has_builtin(__builtin_amdgcn_permlane16_swap)
    auto r = __builtin_amdgcn_permlane16_swap(__builtin_bit_cast(int, x),
                                              __builtin_bit_cast(int, x), false, false);
    return __builtin_bit_cast(float, (int)r[0]) + __builtin_bit_cast(float, (int)r[1]);
#else
    return x + swzf<SWZ_XOR16>(x);
#endif
}
// y[l] = x[l] + x[l^32], pure VALU on gfx950.
__device__ __forceinline__ float sum_xor32(float x) {
#if __has_builtin(__builtin_amdgcn_permlane32_swap)
    auto r = __builtin_amdgcn_permlane32_swap(__builtin_bit_cast(int, x),
                                              __builtin_bit_cast(int, x), false, false);
    return __builtin_bit_cast(float, (int)r[0]) + __builtin_bit_cast(float, (int)r[1]);
#else
    return x + __shfl_xor(x, 32, 64);
#endif
}

__global__ __launch_bounds__(256, 4) void fm_fwd_kernel(
    const int* __restrict__ user,
    const int* __restrict__ item,
    const float* __restrict__ user_emb,
    const float* __restrict__ item_emb,
    const float* __restrict__ w1,
    const float* __restrict__ b1,
    const float* __restrict__ v,
    float* __restrict__ out,
    int B)
{
    __shared__ float vsT[KF * F];   // transposed: vsT[k*F + f] = v[f][k]; 8 KB

    const int tid  = threadIdx.x;
    const int lane = tid & 63;
    const int wv   = tid >> 6;
    // 4 rows per wave; base wave-uniform -> SGPR -> s_load chains for indices
    const int base = __builtin_amdgcn_readfirstlane((int)blockIdx.x * (4*ROWS) + wv * ROWS);

    int ui[ROWS], ti[ROWS];
    #pragma unroll
    for (int r = 0; r < ROWS; ++r) {
        const int i = min(base + r, B - 1);
        ui[r] = user[i];
        ti[r] = item[i];
    }

    // Issue all 8 coalesced 256B row gathers first (deepest-latency: item_emb
    // is 256MB, mostly HBM-miss). They stay in flight across the barrier.
    float xa[ROWS], xb[ROWS];
    #pragma unroll
    for (int r = 0; r < ROWS; ++r) {
        xa[r] = user_emb[(size_t)ui[r] * DIMS + lane];
        xb[r] = item_emb[(size_t)ti[r] * DIMS + lane];
    }
    const float wa = w1[lane], wb = w1[DIMS + lane];
    const float bias = b1[0];

    // Stage v transposed into LDS: one coalesced 8KB global read per block.
    {
        const float4* vg = (const float4*)v;
        float4 p0 = vg[tid * 2 + 0];
        float4 p1 = vg[tid * 2 + 1];
        const int f  = tid >> 1;
        const int k0 = (tid & 1) * 8;
        vsT[(k0+0)*F + f] = p0.x;  vsT[(k0+1)*F + f] = p0.y;
        vsT[(k0+2)*F + f] = p0.z;  vsT[(k0+3)*F + f] = p0.w;
        vsT[(k0+4)*F + f] = p1.x;  vsT[(k0+5)*F + f] = p1.y;
        vsT[(k0+6)*F + f] = p1.z;  vsT[(k0+7)*F + f] = p1.w;
    }
    // LDS-only barrier (gathers not drained; compiler waits vmcnt only for p0/p1).
    asm volatile("s_waitcnt lgkmcnt(0)" ::: "memory");
    __builtin_amdgcn_s_barrier();

    // Single k-loop: one conflict-free ds_read pair feeds all 4 rows.
    float s0[KF], s1[KF], s2[KF], s3[KF];
    float A = 0.f, Bq = 0.f;
    #pragma unroll
    for (int k = 0; k < KF; ++k) {
        const float va = vsT[k * F + lane];
        const float vb = vsT[k * F + DIMS + lane];
        A  += va * va;
        Bq += vb * vb;
        s0[k] = xa[0] * va + xb[0] * vb;
        s1[k] = xa[1] * va + xb[1] * vb;
        s2[k] = xa[2] * va + xb[2] * vb;
        s3[k] = xa[3] * va + xb[3] * vb;
    }
    float c[ROWS];
    #pragma unroll
    for (int r = 0; r < ROWS; ++r)
        c[r] = xa[r]*wa + xb[r]*wb - 0.5f*(xa[r]*xa[r]*A + xb[r]*xb[r]*Bq);

    // Vector-halving reduce over masks 1,2,8 (DPP) and 4 (swizzle), two rows
    // interleaved per pass for ILP. Lane->k bijection permutation irrelevant
    // (we only need sum_k S_k^2).
    #define HALVE2(SA, SB, MV, M, N) { \
        const bool hi = (lane & (M)) != 0; \
        _Pragma("unroll") \
        for (int i = 0; i < (N); ++i) { \
            float kA = hi ? SA[(N)+i] : SA[i]; float dA = hi ? SA[i] : SA[(N)+i]; \
            float kB = hi ? SB[(N)+i] : SB[i]; float dB = hi ? SB[i] : SB[(N)+i]; \
            SA[i] = kA + MV(dA); \
            SB[i] = kB + MV(dB); \
        } }
    #define REDUCE_PAIR(SA, SB, CA, CB) { \
        HALVE2(SA, SB, dppmv<DPP_XOR1>, 1, 8) \
        HALVE2(SA, SB, dppmv<DPP_XOR2>, 2, 4) \
        HALVE2(SA, SB, dppmv<DPP_XOR8>, 8, 2) \
        HALVE2(SA, SB, swzf<SWZ_XOR4>,  4, 1) \
        float svA = sum_xor32(sum_xor16(SA[0])); \
        float svB = sum_xor32(sum_xor16(SB[0])); \
        CA += 0.125f * svA * svA; \
        CB += 0.125f * svB * svB; \
    }
    REDUCE_PAIR(s0, s1, c[0], c[1])
    REDUCE_PAIR(s2, s3, c[2], c[3])
    #undef REDUCE_PAIR
    #undef HALVE2

    // Cross-row combine: 2 vector-halving steps fold 4 rows into one value
    // per lane-coset, then ONE shared butterfly finishes all rows.
    float r0, r1;
    {
        const bool hi = (lane & 1) != 0;
        float k0 = hi ? c[2] : c[0], d0 = hi ? c[0] : c[2];
        float k1 = hi ? c[3] : c[1], d1 = hi ? c[1] : c[3];
        r0 = k0 + dppmv<DPP_XOR1>(d0);
        r1 = k1 + dppmv<DPP_XOR1>(d1);
    }
    float rr;
    {
        const bool hi = (lane & 2) != 0;
        float kk = hi ? r1 : r0, dd = hi ? r0 : r1;
        rr = kk + dppmv<DPP_XOR2>(dd);
    }
    rr += swzf<SWZ_XOR4>(rr);
    rr += dppmv<DPP_XOR8>(rr);
    rr = sum_xor16(rr);
    rr = sum_xor32(rr);

    if (lane < ROWS) {
        const int row = ((lane & 1) << 1) | ((lane >> 1) & 1);
        if (base + row < B)
            out[base + row] = bias + rr;
    }
}

extern "C" void kernel_launch(void* const* d_in, const int* in_sizes, int n_in,
                              void* d_out, int out_size, void* d_ws, size_t ws_size,
                              hipStream_t stream) {
    const int*   user     = (const int*)  d_in[0];
    const int*   item     = (const int*)  d_in[1];
    const float* user_emb = (const float*)d_in[2];
    const float* item_emb = (const float*)d_in[3];
    const float* w1       = (const float*)d_in[4];
    const float* b1       = (const float*)d_in[5];
    const float* v        = (const float*)d_in[6];
    float* out = (float*)d_out;

    const int B = in_sizes[0];
    const int rows_per_block = 4 * ROWS;   // 4 waves x 4 rows
    const int blocks = (B + rows_per_block - 1) / rows_per_block;
    fm_fwd_kernel<<<blocks, 256, 0, stream>>>(user, item, user_emb, item_emb,
                                              w1, b1, v, out, B);
}

// Round 7
// 9.729 us; speedup vs baseline: 5.0931x; 1.0006x over previous
//
#include <hip/hip_runtime.h>

#define DIMS 64
#define KF 16
#define F 128   // 2*DIMS
#define ROWS 4
#define ROWS_PER_BLOCK 16   // 4 waves x ROWS

// DPP lane permute: pure VALU, no LDS pipe, no waitcnt.
template<int CTRL>
__device__ __forceinline__ float dppmv(float x) {
    return __builtin_bit_cast(float,
        __builtin_amdgcn_update_dpp(0, __builtin_bit_cast(int, x), CTRL, 0xF, 0xF, true));
}
// Single-instruction LDS-crossbar swizzle.
template<int PAT>
__device__ __forceinline__ float swzf(float x) {
    return __builtin_bit_cast(float,
        __builtin_amdgcn_ds_swizzle(__builtin_bit_cast(int, x), PAT));
}

#define DPP_XOR1  0xB1   // quad_perm(1,0,3,2)
#define DPP_XOR2  0x4E   // quad_perm(2,3,0,1)
#define DPP_XOR8  0x128  // row_ror:8 (== xor 8 within 16)
#define SWZ_XOR4  0x101F // BitMode xor_mask=4
#define SWZ_XOR16 0x401F // BitMode xor_mask=16

// y[l] = x[l] + x[l^16], pure VALU on gfx950.
__device__ __forceinline__ float sum_xor16(float x) {
#if __has_builtin(__builtin_amdgcn_permlane16_swap)
    auto r = __builtin_amdgcn_permlane16_swap(__builtin_bit_cast(int, x),
                                              __builtin_bit_cast(int, x), false, false);
    return __builtin_bit_cast(float, (int)r[0]) + __builtin_bit_cast(float, (int)r[1]);
#else
    return x + swzf<SWZ_XOR16>(x);
#endif
}
// y[l] = x[l] + x[l^32], pure VALU on gfx950.
__device__ __forceinline__ float sum_xor32(float x) {
#if __has_builtin(__builtin_amdgcn_permlane32_swap)
    auto r = __builtin_amdgcn_permlane32_swap(__builtin_bit_cast(int, x),
                                              __builtin_bit_cast(int, x), false, false);
    return __builtin_bit_cast(float, (int)r[0]) + __builtin_bit_cast(float, (int)r[1]);
#else
    return x + __shfl_xor(x, 32, 64);
#endif
}

__global__ __launch_bounds__(256, 4) void fm_fwd_kernel(
    const int* __restrict__ user,
    const int* __restrict__ item,
    const float* __restrict__ user_emb,
    const float* __restrict__ item_emb,
    const float* __restrict__ w1,
    const float* __restrict__ b1,
    const float* __restrict__ v,
    float* __restrict__ out,
    int B)
{
    __shared__ float vsT[KF * F];   // vsT[k*F + f] = v[f][k]; 8 KB

    const int tid  = threadIdx.x;
    const int lane = tid & 63;
    const int wv   = tid >> 6;
    const int q    = lane & 31;     // feature pair index within half
    const int half = lane >> 5;     // 0 = user half, 1 = item half

    // ---- 1. v staging loads FIRST: oldest vmem, so the ds_writes below
    //         wait at vmcnt(N) and leave the row gathers in flight. ----
    const float4* vg = (const float4*)v;
    const float4 p0 = vg[tid * 2 + 0];
    const float4 p1 = vg[tid * 2 + 1];

    // ---- 2. indices: one s_load_dwordx4 per table on the fast path ----
    const int base = __builtin_amdgcn_readfirstlane(
        (int)blockIdx.x * ROWS_PER_BLOCK + wv * ROWS);
    int ui[ROWS], ti[ROWS];
    if ((int)(blockIdx.x + 1) * ROWS_PER_BLOCK <= B) {
        const int4 uu = *(const int4*)(user + base);
        const int4 tt = *(const int4*)(item + base);
        ui[0] = uu.x; ui[1] = uu.y; ui[2] = uu.z; ui[3] = uu.w;
        ti[0] = tt.x; ti[1] = tt.y; ti[2] = tt.z; ti[3] = tt.w;
    } else {
        #pragma unroll
        for (int r = 0; r < ROWS; ++r) {
            const int i = min(base + r, B - 1);
            ui[r] = user[i];
            ti[r] = item[i];
        }
    }

    // ---- 3. paired gathers: ONE instruction per row. Lanes 0-31 fetch the
    //         user half (float2 each), lanes 32-63 the item half. ----
    float2 x[ROWS];
    #pragma unroll
    for (int r = 0; r < ROWS; ++r) {
        const float* src = half ? (item_emb + (size_t)ti[r] * DIMS)
                                : (user_emb + (size_t)ui[r] * DIMS);
        x[r] = *(const float2*)(src + 2 * q);
    }

    // ---- 4. w1 (one float2 per lane) + bias ----
    const float2 w2 = *(const float2*)(w1 + half * DIMS + 2 * q);
    const float bias = b1[0];

    // ---- 5. stage v transposed into LDS (consumes only p0/p1 -> vmcnt
    //         leaves gathers outstanding) ----
    {
        const int f  = tid >> 1;
        const int k0 = (tid & 1) * 8;
        vsT[(k0+0)*F + f] = p0.x;  vsT[(k0+1)*F + f] = p0.y;
        vsT[(k0+2)*F + f] = p0.z;  vsT[(k0+3)*F + f] = p0.w;
        vsT[(k0+4)*F + f] = p1.x;  vsT[(k0+5)*F + f] = p1.y;
        vsT[(k0+6)*F + f] = p1.z;  vsT[(k0+7)*F + f] = p1.w;
    }
    // LDS-only barrier: no vmem drain of the row gathers.
    asm volatile("s_waitcnt lgkmcnt(0)" ::: "memory");
    __builtin_amdgcn_s_barrier();

    // ---- 6. k-loop: lane reads its feature pair (f, f+1) for each k via a
    //         single conflict-free ds_read_b64; feeds all 4 rows. ----
    // float2 element index: (k*F + half*DIMS + 2q)/2 = k*64 + lane.
    const float2* vs2 = ((const float2*)vsT) + lane;
    float s0[KF], s1[KF], s2[KF], s3[KF];
    float A0 = 0.f, A1 = 0.f;   // sum_k v_{f,k}^2 , v_{f+1,k}^2 (per-lane)
    #pragma unroll
    for (int k = 0; k < KF; ++k) {
        const float2 vv = vs2[k * 64];
        A0 += vv.x * vv.x;
        A1 += vv.y * vv.y;
        s0[k] = x[0].x * vv.x + x[0].y * vv.y;
        s1[k] = x[1].x * vv.x + x[1].y * vv.y;
        s2[k] = x[2].x * vv.x + x[2].y * vv.y;
        s3[k] = x[3].x * vv.x + x[3].y * vv.y;
    }
    float c[ROWS];
    #pragma unroll
    for (int r = 0; r < ROWS; ++r)
        c[r] = x[r].x * w2.x + x[r].y * w2.y
             - 0.5f * (x[r].x * x[r].x * A0 + x[r].y * x[r].y * A1);

    // ---- 7. reductions (identical structure to R6; lane->k bijection
    //         permutation irrelevant since we sum S_k^2 over all k) ----
    #define HALVE2(SA, SB, MV, M, N) { \
        const bool hi = (lane & (M)) != 0; \
        _Pragma("unroll") \
        for (int i = 0; i < (N); ++i) { \
            float kA = hi ? SA[(N)+i] : SA[i]; float dA = hi ? SA[i] : SA[(N)+i]; \
            float kB = hi ? SB[(N)+i] : SB[i]; float dB = hi ? SB[i] : SB[(N)+i]; \
            SA[i] = kA + MV(dA); \
            SB[i] = kB + MV(dB); \
        } }
    #define REDUCE_PAIR(SA, SB, CA, CB) { \
        HALVE2(SA, SB, dppmv<DPP_XOR1>, 1, 8) \
        HALVE2(SA, SB, dppmv<DPP_XOR2>, 2, 4) \
        HALVE2(SA, SB, dppmv<DPP_XOR8>, 8, 2) \
        HALVE2(SA, SB, swzf<SWZ_XOR4>,  4, 1) \
        float svA = sum_xor32(sum_xor16(SA[0])); \
        float svB = sum_xor32(sum_xor16(SB[0])); \
        CA += 0.125f * svA * svA; \
        CB += 0.125f * svB * svB; \
    }
    REDUCE_PAIR(s0, s1, c[0], c[1])
    REDUCE_PAIR(s2, s3, c[2], c[3])
    #undef REDUCE_PAIR
    #undef HALVE2

    // Cross-row combine: fold 4 rows into one value per lane-coset, then one
    // shared butterfly finishes all rows.
    float r0, r1;
    {
        const bool hi = (lane & 1) != 0;
        float k0 = hi ? c[2] : c[0], d0 = hi ? c[0] : c[2];
        float k1 = hi ? c[3] : c[1], d1 = hi ? c[1] : c[3];
        r0 = k0 + dppmv<DPP_XOR1>(d0);
        r1 = k1 + dppmv<DPP_XOR1>(d1);
    }
    float rr;
    {
        const bool hi = (lane & 2) != 0;
        float kk = hi ? r1 : r0, dd = hi ? r0 : r1;
        rr = kk + dppmv<DPP_XOR2>(dd);
    }
    rr += swzf<SWZ_XOR4>(rr);
    rr += dppmv<DPP_XOR8>(rr);
    rr = sum_xor16(rr);
    rr = sum_xor32(rr);

    if (lane < ROWS) {
        const int row = ((lane & 1) << 1) | ((lane >> 1) & 1);
        if (base + row < B)
            out[base + row] = bias + rr;
    }
}

extern "C" void kernel_launch(void* const* d_in, const int* in_sizes, int n_in,
                              void* d_out, int out_size, void* d_ws, size_t ws_size,
                              hipStream_t stream) {
    const int*   user     = (const int*)  d_in[0];
    const int*   item     = (const int*)  d_in[1];
    const float* user_emb = (const float*)d_in[2];
    const float* item_emb = (const float*)d_in[3];
    const float* w1       = (const float*)d_in[4];
    const float* b1       = (const float*)d_in[5];
    const float* v        = (const float*)d_in[6];
    float* out = (float*)d_out;

    const int B = in_sizes[0];
    const int blocks = (B + ROWS_PER_BLOCK - 1) / ROWS_PER_BLOCK;
    fm_fwd_kernel<<<blocks, 256, 0, stream>>>(user, item, user_emb, item_emb,
                                              w1, b1, v, out, B);
}